// Round 5
// baseline (9577.750 us; speedup 1.0000x reference)
//
#include <hip/hip_runtime.h>

#define B_SZ 2048
#define FEAT 840
#define HID  256
#define LAT  128
#define NQ   12
#define NEMB 512

#define T_SUB 24
#define HSTR  27    // h1 tile stride (T_SUB+2, +1 pad)
#define H2STR 25    // h2 tile stride (T_SUB, +1 pad)

// numpy pairwise 8-accumulator combine: ((r0+r1)+(r2+r3))+((r4+r5)+(r6+r7))
__device__ __forceinline__ float np8_combine(const float* r) {
    float sA = __fadd_rn(r[0], r[1]);
    float sB = __fadd_rn(r[2], r[3]);
    float sC = __fadd_rn(r[4], r[5]);
    float sD = __fadd_rn(r[6], r[7]);
    return __fadd_rn(__fadd_rn(sA, sB), __fadd_rn(sC, sD));
}

// ---------------- encoder, numpy-f32 bit-faithful ----------------
// one block per batch row; 256 threads = 32 l-groups(4 l) x 8 t-groups(3 t).
__global__ __launch_bounds__(256) void enc32_kernel(
    const float* __restrict__ x,  const float* __restrict__ w1,
    const float* __restrict__ b1, const float* __restrict__ w2,
    const float* __restrict__ b2, float* __restrict__ zout)
{
    __shared__ float xp[FEAT + 4];        // xp[i] = x[i-1], zero-padded
    __shared__ float h1s[HID * HSTR];     // 27648 B
    __shared__ float h2t[LAT * H2STR];    // 12800 B
    __shared__ float leafs[LAT * 8];      // 4096 B

    const int tid = threadIdx.x;
    const int b   = blockIdx.x;
    const int tx  = tid & 7;        // t-group (3 t's)
    const int ly  = tid >> 3;       // l-group (4 l's)
    const int u0  = tx * 3;

    const float wA = w1[tid*3+0], wB = w1[tid*3+1], wC = w1[tid*3+2];
    const float b1c = b1[tid];
    float b2v[4];
#pragma unroll
    for (int j = 0; j < 4; ++j) b2v[j] = b2[ly*4 + j];

    for (int i = tid; i < FEAT + 2; i += 256)
        xp[i] = (i >= 1 && i <= FEAT) ? x[(size_t)b*FEAT + i - 1] : 0.f;

    // numpy pairwise-840 leaf state (threads 0..127, one l each)
    float racc[8];
    int leaf_id = 0, leaf_pos = 0;
#pragma unroll
    for (int j = 0; j < 8; ++j) racc[j] = 0.f;

    __syncthreads();
    for (int t0 = 0; t0 < FEAT; t0 += T_SUB) {
        // phase A: h1[c=tid][tp] f32 exact: relu(((w0*x0 + w1*x1) + w2*x2) + b1)
        for (int tp = 0; tp < T_SUB + 2; ++tp) {
            int tg = t0 - 1 + tp;
            float v = 0.f;
            if (tg >= 0 && tg < FEAT) {
                float m0 = __fmul_rn(wA, xp[tg]);
                float m1 = __fmul_rn(wB, xp[tg+1]);
                float m2 = __fmul_rn(wC, xp[tg+2]);
                float s  = __fadd_rn(__fadd_rn(m0, m1), m2);
                s = __fadd_rn(s, b1c);
                v = s > 0.f ? s : 0.f;
            }
            h1s[tid*HSTR + tp] = v;
        }
        __syncthreads();

        // phase B: conv2 = 3 k-matmuls (sequential-c fma chains), combined
        // h2 = fl(fl(m0+m1)+m2); + b2; relu
        float sk[4][3][3];
#pragma unroll
        for (int j = 0; j < 4; ++j)
#pragma unroll
            for (int i = 0; i < 3; ++i)
#pragma unroll
                for (int k = 0; k < 3; ++k) sk[j][i][k] = 0.f;

        const float* __restrict__ wp = w2 + (size_t)(ly*4)*768;
        for (int c2 = 0; c2 < HID; ++c2) {
            const float* hb = &h1s[c2*HSTR + u0];
            float hv0 = hb[0], hv1 = hb[1], hv2 = hb[2], hv3 = hb[3], hv4 = hb[4];
#pragma unroll
            for (int j = 0; j < 4; ++j) {
                float wa = wp[j*768 + c2*3 + 0];
                float wb = wp[j*768 + c2*3 + 1];
                float wc = wp[j*768 + c2*3 + 2];
                sk[j][0][0] = __fmaf_rn(wa, hv0, sk[j][0][0]);
                sk[j][0][1] = __fmaf_rn(wb, hv1, sk[j][0][1]);
                sk[j][0][2] = __fmaf_rn(wc, hv2, sk[j][0][2]);
                sk[j][1][0] = __fmaf_rn(wa, hv1, sk[j][1][0]);
                sk[j][1][1] = __fmaf_rn(wb, hv2, sk[j][1][1]);
                sk[j][1][2] = __fmaf_rn(wc, hv3, sk[j][1][2]);
                sk[j][2][0] = __fmaf_rn(wa, hv2, sk[j][2][0]);
                sk[j][2][1] = __fmaf_rn(wb, hv3, sk[j][2][1]);
                sk[j][2][2] = __fmaf_rn(wc, hv4, sk[j][2][2]);
            }
        }
#pragma unroll
        for (int j = 0; j < 4; ++j)
#pragma unroll
            for (int i = 0; i < 3; ++i) {
                float hh = __fadd_rn(__fadd_rn(sk[j][i][0], sk[j][i][1]), sk[j][i][2]);
                hh = __fadd_rn(hh, b2v[j]);
                hh = hh > 0.f ? hh : 0.f;
                h2t[(ly*4 + j)*H2STR + u0 + i] = hh;
            }
        __syncthreads();

        // reducer: threads 0..127 ingest 24 t's in order into numpy pairwise leaves
        if (tid < LAT) {
            for (int tt = 0; tt < T_SUB; ++tt) {
                float v = h2t[tid*H2STR + tt];
                int j = leaf_pos & 7;
                racc[j] = (leaf_pos < 8) ? v : __fadd_rn(racc[j], v);
                ++leaf_pos;
                int llen = (leaf_id == 7) ? 112 : 104;
                if (leaf_pos == llen) {
                    leafs[tid*8 + leaf_id] = np8_combine(racc);
                    ++leaf_id; leaf_pos = 0;
                }
            }
        }
        __syncthreads();
    }

    // numpy pairwise-840 recombination:
    // total = ((L01+L23)) + ((L45)+(L67)) per recursion (416,424)->(208,208|208,216)
    if (tid < LAT) {
        const float* L = &leafs[tid*8];
        float s0 = __fadd_rn(L[0], L[1]);   // [0,208)
        float s1 = __fadd_rn(L[2], L[3]);   // [208,416)
        float sA = __fadd_rn(s0, s1);       // [0,416)
        float s2 = __fadd_rn(L[4], L[5]);   // [416,624)
        float s3 = __fadd_rn(L[6], L[7]);   // [624,840)
        float sB = __fadd_rn(s2, s3);       // [416,840)
        float tot = __fadd_rn(sA, sB);
        zout[(size_t)b*LAT + tid] = __fdiv_rn(tot, 840.0f);
    }
}

// ---------------- RVQ, numpy-f32 bit-faithful ----------------
// one block per batch row; 256 threads, codes {2t, 2t+1}.
// d = fl(fl(A - fl(2*dot)) + cn); A,cn = numpy pairwise-128; dot = seq fma.
__global__ __launch_bounds__(256) void rvq32_kernel(
    const float* __restrict__ cb, const float* __restrict__ z,
    float* __restrict__ zqout, float* __restrict__ oidx)
{
    __shared__ float rr[LAT];
    __shared__ float Ash;
    __shared__ float redd[256];
    __shared__ int   rede[256];
    __shared__ float sredd[64];
    __shared__ int   srede[64];
    __shared__ int   beste;
    __shared__ float qv[NQ * LAT];   // selected code values per step

    const int tid = threadIdx.x;
    const int b   = blockIdx.x;

    if (tid < LAT) rr[tid] = z[(size_t)b*LAT + tid];
    __syncthreads();

    for (int q = 0; q < NQ; ++q) {
        const float* __restrict__ cbq = cb + (size_t)q * NEMB * LAT;

        // A = numpy pairwise-128 of fl(r*r)
        if (tid == 0) {
            float r8[8];
#pragma unroll
            for (int j = 0; j < 8; ++j) r8[j] = __fmul_rn(rr[j], rr[j]);
            for (int i = 8; i < LAT; i += 8)
#pragma unroll
                for (int j = 0; j < 8; ++j)
                    r8[j] = __fadd_rn(r8[j], __fmul_rn(rr[i+j], rr[i+j]));
            Ash = np8_combine(r8);
        }
        __syncthreads();

        float dmin = 0.f; int emin = 0;
#pragma unroll
        for (int h = 0; h < 2; ++h) {
            int e = 2*tid + h;
            const float* __restrict__ cp = cbq + (size_t)e*LAT;
            float dot = 0.f;
            float c8[8];
#pragma unroll
            for (int j = 0; j < 8; ++j) {
                float c = cp[j];
                c8[j] = __fmul_rn(c, c);
                dot = __fmaf_rn(c, rr[j], dot);
            }
            for (int i = 8; i < LAT; i += 8)
#pragma unroll
                for (int j = 0; j < 8; ++j) {
                    float c = cp[i+j];
                    dot = __fmaf_rn(c, rr[i+j], dot);
                    c8[j] = __fadd_rn(c8[j], __fmul_rn(c, c));
                }
            float cn = np8_combine(c8);
            float G  = __fmul_rn(2.0f, dot);
            float d  = __fadd_rn(__fsub_rn(Ash, G), cn);
            if (h == 0) { dmin = d; emin = e; }
            else if (d < dmin) { dmin = d; emin = e; }
        }
        redd[tid] = dmin; rede[tid] = emin;
        __syncthreads();

        if (tid < 64) {   // 4 consecutive threads = codes 8t..8t+7 ascending
            float bb = redd[tid*4]; int ee = rede[tid*4];
            for (int j = 1; j < 4; ++j) {
                float dj = redd[tid*4 + j];
                if (dj < bb) { bb = dj; ee = rede[tid*4 + j]; }
            }
            sredd[tid] = bb; srede[tid] = ee;
        }
        __syncthreads();
        if (tid == 0) {
            float bb = sredd[0]; int ee = srede[0];
            for (int j = 1; j < 64; ++j) {
                float dj = sredd[j];
                if (dj < bb) { bb = dj; ee = srede[j]; }
            }
            beste = ee;
            oidx[(size_t)b*NQ + q] = (float)ee;
        }
        __syncthreads();

        if (tid < LAT) {
            float cv = cbq[(size_t)beste*LAT + tid];
            qv[q*LAT + tid] = cv;
            rr[tid] = __fsub_rn(rr[tid], cv);   // fl32(r - q), numpy order
        }
        __syncthreads();
    }

    // zq = qs.sum(axis=0): outer-axis reduce -> sequential adds q=0..11
    if (tid < LAT) {
        float s = qv[tid];
        for (int s2 = 1; s2 < NQ; ++s2)
            s = __fadd_rn(s, qv[s2*LAT + tid]);
        zqout[(size_t)b*LAT + tid] = s;
    }
}

extern "C" void kernel_launch(void* const* d_in, const int* in_sizes, int n_in,
                              void* d_out, int out_size, void* d_ws, size_t ws_size,
                              hipStream_t stream)
{
    (void)in_sizes; (void)n_in; (void)out_size; (void)d_ws; (void)ws_size;
    const float* x  = (const float*)d_in[0];
    const float* w1 = (const float*)d_in[1];
    const float* b1 = (const float*)d_in[2];
    const float* w2 = (const float*)d_in[3];
    const float* b2 = (const float*)d_in[4];
    const float* cb = (const float*)d_in[5];

    float* out  = (float*)d_out;
    float* zq   = out;                         // 2048*1*128 floats
    float* oidx = out + (size_t)B_SZ * LAT;    // 2048*1*12 floats

    // z (f32, numpy-faithful) staged in the zq output slot, then overwritten
    enc32_kernel<<<B_SZ, 256, 0, stream>>>(x, w1, b1, w2, b2, zq);
    rvq32_kernel<<<B_SZ, 256, 0, stream>>>(cb, zq, zq, oidx);
}

// Round 6
// 7940.000 us; speedup vs baseline: 1.2063x; 1.2063x over previous
//
#include <hip/hip_runtime.h>

#define B_SZ 2048
#define FEAT 840
#define HID  256
#define LAT  128
#define NQ   12
#define NEMB 512

#define T_SUB 24
#define HSTR  27    // h1 tile stride (T_SUB+2, +1 pad)
#define H2STR 25    // h2 tile stride (T_SUB, +1 pad)

// numpy pairwise 8-accumulator combine: ((r0+r1)+(r2+r3))+((r4+r5)+(r6+r7))
__device__ __forceinline__ float np8_combine(const float* r) {
    float sA = __fadd_rn(r[0], r[1]);
    float sB = __fadd_rn(r[2], r[3]);
    float sC = __fadd_rn(r[4], r[5]);
    float sD = __fadd_rn(r[6], r[7]);
    return __fadd_rn(__fadd_rn(sA, sB), __fadd_rn(sC, sD));
}

// ---------------- w2 repack: w2r[c2][ly][j*3+k] ----------------
// 256*32*12 floats = 393216 B; gives each thread 3 contiguous float4s per c2.
__global__ __launch_bounds__(256) void w2r_kernel(const float* __restrict__ w2,
                                                  float* __restrict__ w2r)
{
    int p = blockIdx.x * 256 + threadIdx.x;          // [0, 256*384)
    if (p >= HID * 384) return;
    int c2 = p / 384, r = p - c2 * 384;
    int ly = r / 12, jk = r - ly * 12;
    int j = jk / 3, k = jk - j * 3;
    w2r[p] = w2[(size_t)(ly*4 + j)*768 + c2*3 + k];
}

// ---------------- encoder, numpy-f32 bit-faithful ----------------
// one block per batch row; 256 threads = 32 l-groups(4 l) x 8 t-groups(3 t).
template <int USE_WR>
__global__ __launch_bounds__(256) void enc32_kernel(
    const float* __restrict__ x,  const float* __restrict__ w1,
    const float* __restrict__ b1, const float* __restrict__ w2,
    const float* __restrict__ w2r,
    const float* __restrict__ b2, float* __restrict__ zout)
{
    __shared__ float xp[FEAT + 4];        // xp[i] = x[i-1], zero-padded
    __shared__ float h1s[HID * HSTR];     // 27648 B
    __shared__ float h2t[LAT * H2STR];    // 12800 B
    __shared__ float leafs[LAT * 8];      // 4096 B

    const int tid = threadIdx.x;
    const int b   = blockIdx.x;
    const int tx  = tid & 7;        // t-group (3 t's)
    const int ly  = tid >> 3;       // l-group (4 l's)
    const int u0  = tx * 3;

    const float wA = w1[tid*3+0], wB = w1[tid*3+1], wC = w1[tid*3+2];
    const float b1c = b1[tid];
    float b2v[4];
#pragma unroll
    for (int j = 0; j < 4; ++j) b2v[j] = b2[ly*4 + j];

    for (int i = tid; i < FEAT + 2; i += 256)
        xp[i] = (i >= 1 && i <= FEAT) ? x[(size_t)b*FEAT + i - 1] : 0.f;

    // numpy pairwise-840 leaf state (threads 0..127, one l each)
    float racc[8];
    int leaf_id = 0, leaf_pos = 0;
#pragma unroll
    for (int j = 0; j < 8; ++j) racc[j] = 0.f;

    __syncthreads();
    for (int t0 = 0; t0 < FEAT; t0 += T_SUB) {
        // phase A: h1[c=tid][tp] f32 exact: relu(((w0*x0 + w1*x1) + w2*x2) + b1)
        for (int tp = 0; tp < T_SUB + 2; ++tp) {
            int tg = t0 - 1 + tp;
            float v = 0.f;
            if (tg >= 0 && tg < FEAT) {
                float m0 = __fmul_rn(wA, xp[tg]);
                float m1 = __fmul_rn(wB, xp[tg+1]);
                float m2 = __fmul_rn(wC, xp[tg+2]);
                float s  = __fadd_rn(__fadd_rn(m0, m1), m2);
                s = __fadd_rn(s, b1c);
                v = s > 0.f ? s : 0.f;
            }
            h1s[tid*HSTR + tp] = v;
        }
        __syncthreads();

        // phase B: conv2 = 3 k-matmuls (sequential-c fma chains, c2 ascending)
        float sk[4][3][3];
#pragma unroll
        for (int j = 0; j < 4; ++j)
#pragma unroll
            for (int i = 0; i < 3; ++i)
#pragma unroll
                for (int k = 0; k < 3; ++k) sk[j][i][k] = 0.f;

        if (USE_WR) {
            const float* __restrict__ wbase = w2r + ly*12;
            for (int c2 = 0; c2 < HID; c2 += 2) {
                // ---- all loads first (wide, imm-offset friendly) ----
                const float4* p0 = (const float4*)(wbase + (size_t)c2*384);
                const float4* p1 = (const float4*)(wbase + (size_t)(c2+1)*384);
                float4 a0 = p0[0], a1 = p0[1], a2 = p0[2];
                float4 b0 = p1[0], b1_ = p1[1], b2_ = p1[2];
                const float* hb0 = &h1s[c2*HSTR + u0];
                const float* hb1 = &h1s[(c2+1)*HSTR + u0];
                float g0 = hb0[0], g1 = hb0[1], g2 = hb0[2], g3 = hb0[3], g4 = hb0[4];
                float f0 = hb1[0], f1 = hb1[1], f2 = hb1[2], f3 = hb1[3], f4 = hb1[4];

                float w0[12] = {a0.x,a0.y,a0.z,a0.w, a1.x,a1.y,a1.z,a1.w, a2.x,a2.y,a2.z,a2.w};
                float w1v[12] = {b0.x,b0.y,b0.z,b0.w, b1_.x,b1_.y,b1_.z,b1_.w, b2_.x,b2_.y,b2_.z,b2_.w};

                // ---- c2 (even) ----
#pragma unroll
                for (int j = 0; j < 4; ++j) {
                    float wa = w0[j*3+0], wb = w0[j*3+1], wc = w0[j*3+2];
                    sk[j][0][0] = __fmaf_rn(wa, g0, sk[j][0][0]);
                    sk[j][0][1] = __fmaf_rn(wb, g1, sk[j][0][1]);
                    sk[j][0][2] = __fmaf_rn(wc, g2, sk[j][0][2]);
                    sk[j][1][0] = __fmaf_rn(wa, g1, sk[j][1][0]);
                    sk[j][1][1] = __fmaf_rn(wb, g2, sk[j][1][1]);
                    sk[j][1][2] = __fmaf_rn(wc, g3, sk[j][1][2]);
                    sk[j][2][0] = __fmaf_rn(wa, g2, sk[j][2][0]);
                    sk[j][2][1] = __fmaf_rn(wb, g3, sk[j][2][1]);
                    sk[j][2][2] = __fmaf_rn(wc, g4, sk[j][2][2]);
                }
                // ---- c2+1 (odd) ----
#pragma unroll
                for (int j = 0; j < 4; ++j) {
                    float wa = w1v[j*3+0], wb = w1v[j*3+1], wc = w1v[j*3+2];
                    sk[j][0][0] = __fmaf_rn(wa, f0, sk[j][0][0]);
                    sk[j][0][1] = __fmaf_rn(wb, f1, sk[j][0][1]);
                    sk[j][0][2] = __fmaf_rn(wc, f2, sk[j][0][2]);
                    sk[j][1][0] = __fmaf_rn(wa, f1, sk[j][1][0]);
                    sk[j][1][1] = __fmaf_rn(wb, f2, sk[j][1][1]);
                    sk[j][1][2] = __fmaf_rn(wc, f3, sk[j][1][2]);
                    sk[j][2][0] = __fmaf_rn(wa, f2, sk[j][2][0]);
                    sk[j][2][1] = __fmaf_rn(wb, f3, sk[j][2][1]);
                    sk[j][2][2] = __fmaf_rn(wc, f4, sk[j][2][2]);
                }
            }
        } else {
            const float* __restrict__ wp = w2 + (size_t)(ly*4)*768;
            for (int c2 = 0; c2 < HID; ++c2) {
                const float* hb = &h1s[c2*HSTR + u0];
                float hv0 = hb[0], hv1 = hb[1], hv2 = hb[2], hv3 = hb[3], hv4 = hb[4];
#pragma unroll
                for (int j = 0; j < 4; ++j) {
                    float wa = wp[j*768 + c2*3 + 0];
                    float wb = wp[j*768 + c2*3 + 1];
                    float wc = wp[j*768 + c2*3 + 2];
                    sk[j][0][0] = __fmaf_rn(wa, hv0, sk[j][0][0]);
                    sk[j][0][1] = __fmaf_rn(wb, hv1, sk[j][0][1]);
                    sk[j][0][2] = __fmaf_rn(wc, hv2, sk[j][0][2]);
                    sk[j][1][0] = __fmaf_rn(wa, hv1, sk[j][1][0]);
                    sk[j][1][1] = __fmaf_rn(wb, hv2, sk[j][1][1]);
                    sk[j][1][2] = __fmaf_rn(wc, hv3, sk[j][1][2]);
                    sk[j][2][0] = __fmaf_rn(wa, hv2, sk[j][2][0]);
                    sk[j][2][1] = __fmaf_rn(wb, hv3, sk[j][2][1]);
                    sk[j][2][2] = __fmaf_rn(wc, hv4, sk[j][2][2]);
                }
            }
        }

        // h2 = fl(fl(m0+m1)+m2) + b2, relu  -> LDS for the t-order reducer
#pragma unroll
        for (int j = 0; j < 4; ++j)
#pragma unroll
            for (int i = 0; i < 3; ++i) {
                float hh = __fadd_rn(__fadd_rn(sk[j][i][0], sk[j][i][1]), sk[j][i][2]);
                hh = __fadd_rn(hh, b2v[j]);
                hh = hh > 0.f ? hh : 0.f;
                h2t[(ly*4 + j)*H2STR + u0 + i] = hh;
            }
        __syncthreads();

        // reducer: threads 0..127 ingest 24 t's in order into numpy pairwise leaves
        if (tid < LAT) {
            for (int tt = 0; tt < T_SUB; ++tt) {
                float v = h2t[tid*H2STR + tt];
                int j = leaf_pos & 7;
                racc[j] = (leaf_pos < 8) ? v : __fadd_rn(racc[j], v);
                ++leaf_pos;
                int llen = (leaf_id == 7) ? 112 : 104;
                if (leaf_pos == llen) {
                    leafs[tid*8 + leaf_id] = np8_combine(racc);
                    ++leaf_id; leaf_pos = 0;
                }
            }
        }
        __syncthreads();
    }

    // numpy pairwise-840 recombination
    if (tid < LAT) {
        const float* L = &leafs[tid*8];
        float s0 = __fadd_rn(L[0], L[1]);
        float s1 = __fadd_rn(L[2], L[3]);
        float sA = __fadd_rn(s0, s1);
        float s2 = __fadd_rn(L[4], L[5]);
        float s3 = __fadd_rn(L[6], L[7]);
        float sB = __fadd_rn(s2, s3);
        float tot = __fadd_rn(sA, sB);
        zout[(size_t)b*LAT + tid] = __fdiv_rn(tot, 840.0f);
    }
}

// ---------------- RVQ, numpy-f32 bit-faithful ----------------
__global__ __launch_bounds__(256) void rvq32_kernel(
    const float* __restrict__ cb, const float* __restrict__ z,
    float* __restrict__ zqout, float* __restrict__ oidx)
{
    __shared__ float rr[LAT];
    __shared__ float Ash;
    __shared__ float redd[256];
    __shared__ int   rede[256];
    __shared__ float sredd[64];
    __shared__ int   srede[64];
    __shared__ int   beste;
    __shared__ float qv[NQ * LAT];

    const int tid = threadIdx.x;
    const int b   = blockIdx.x;

    if (tid < LAT) rr[tid] = z[(size_t)b*LAT + tid];
    __syncthreads();

    for (int q = 0; q < NQ; ++q) {
        const float* __restrict__ cbq = cb + (size_t)q * NEMB * LAT;

        if (tid == 0) {
            float r8[8];
#pragma unroll
            for (int j = 0; j < 8; ++j) r8[j] = __fmul_rn(rr[j], rr[j]);
            for (int i = 8; i < LAT; i += 8)
#pragma unroll
                for (int j = 0; j < 8; ++j)
                    r8[j] = __fadd_rn(r8[j], __fmul_rn(rr[i+j], rr[i+j]));
            Ash = np8_combine(r8);
        }
        __syncthreads();

        float dmin = 0.f; int emin = 0;
#pragma unroll
        for (int h = 0; h < 2; ++h) {
            int e = 2*tid + h;
            const float* __restrict__ cp = cbq + (size_t)e*LAT;
            float dot = 0.f;
            float c8[8];
#pragma unroll
            for (int j = 0; j < 8; ++j) {
                float c = cp[j];
                c8[j] = __fmul_rn(c, c);
                dot = __fmaf_rn(c, rr[j], dot);
            }
            for (int i = 8; i < LAT; i += 8)
#pragma unroll
                for (int j = 0; j < 8; ++j) {
                    float c = cp[i+j];
                    dot = __fmaf_rn(c, rr[i+j], dot);
                    c8[j] = __fadd_rn(c8[j], __fmul_rn(c, c));
                }
            float cn = np8_combine(c8);
            float G  = __fmul_rn(2.0f, dot);
            float d  = __fadd_rn(__fsub_rn(Ash, G), cn);
            if (h == 0) { dmin = d; emin = e; }
            else if (d < dmin) { dmin = d; emin = e; }
        }
        redd[tid] = dmin; rede[tid] = emin;
        __syncthreads();

        if (tid < 64) {
            float bb = redd[tid*4]; int ee = rede[tid*4];
            for (int j = 1; j < 4; ++j) {
                float dj = redd[tid*4 + j];
                if (dj < bb) { bb = dj; ee = rede[tid*4 + j]; }
            }
            sredd[tid] = bb; srede[tid] = ee;
        }
        __syncthreads();
        if (tid == 0) {
            float bb = sredd[0]; int ee = srede[0];
            for (int j = 1; j < 64; ++j) {
                float dj = sredd[j];
                if (dj < bb) { bb = dj; ee = srede[j]; }
            }
            beste = ee;
            oidx[(size_t)b*NQ + q] = (float)ee;
        }
        __syncthreads();

        if (tid < LAT) {
            float cv = cbq[(size_t)beste*LAT + tid];
            qv[q*LAT + tid] = cv;
            rr[tid] = __fsub_rn(rr[tid], cv);
        }
        __syncthreads();
    }

    if (tid < LAT) {
        float s = qv[tid];
        for (int s2 = 1; s2 < NQ; ++s2)
            s = __fadd_rn(s, qv[s2*LAT + tid]);
        zqout[(size_t)b*LAT + tid] = s;
    }
}

extern "C" void kernel_launch(void* const* d_in, const int* in_sizes, int n_in,
                              void* d_out, int out_size, void* d_ws, size_t ws_size,
                              hipStream_t stream)
{
    (void)in_sizes; (void)n_in; (void)out_size;
    const float* x  = (const float*)d_in[0];
    const float* w1 = (const float*)d_in[1];
    const float* b1 = (const float*)d_in[2];
    const float* w2 = (const float*)d_in[3];
    const float* b2 = (const float*)d_in[4];
    const float* cb = (const float*)d_in[5];

    float* out  = (float*)d_out;
    float* zq   = out;                         // 2048*1*128 floats
    float* oidx = out + (size_t)B_SZ * LAT;    // 2048*1*12 floats

    const size_t w2r_bytes = (size_t)HID * 384 * sizeof(float);  // 393216

    if (ws_size >= w2r_bytes) {
        float* w2r = (float*)d_ws;
        w2r_kernel<<<(HID*384 + 255)/256, 256, 0, stream>>>(w2, w2r);
        enc32_kernel<1><<<B_SZ, 256, 0, stream>>>(x, w1, b1, w2, w2r, b2, zq);
    } else {
        enc32_kernel<0><<<B_SZ, 256, 0, stream>>>(x, w1, b1, w2, nullptr, b2, zq);
    }
    rvq32_kernel<<<B_SZ, 256, 0, stream>>>(cb, zq, zq, oidx);
}

// Round 7
// 6511.035 us; speedup vs baseline: 1.4710x; 1.2195x over previous
//
#include <hip/hip_runtime.h>

#define B_SZ 2048
#define FEAT 840
#define HID  256
#define LAT  128
#define NQ   12
#define NEMB 512

#define T_SUB 40
#define HSTR  43    // h1 tile stride (T_SUB+2, +1 pad, odd)
#define H2STR 41    // h2 stride (T_SUB+1, odd); h2 aliased into h1s (20992 <= 44032)

// numpy pairwise 8-accumulator combine: ((r0+r1)+(r2+r3))+((r4+r5)+(r6+r7))
__device__ __forceinline__ float np8_combine(const float* r) {
    float sA = __fadd_rn(r[0], r[1]);
    float sB = __fadd_rn(r[2], r[3]);
    float sC = __fadd_rn(r[4], r[5]);
    float sD = __fadd_rn(r[6], r[7]);
    return __fadd_rn(__fadd_rn(sA, sB), __fadd_rn(sC, sD));
}

// ---------------- w2 repack: w2r[c2][ly][j*3+k] ----------------
__global__ __launch_bounds__(256) void w2r_kernel(const float* __restrict__ w2,
                                                  float* __restrict__ w2r)
{
    int p = blockIdx.x * 256 + threadIdx.x;          // [0, 256*384)
    if (p >= HID * 384) return;
    int c2 = p / 384, r = p - c2 * 384;
    int ly = r / 12, jk = r - ly * 12;
    int j = jk / 3, k = jk - j * 3;
    w2r[p] = w2[(size_t)(ly*4 + j)*768 + c2*3 + k];
}

// ---------------- encoder, numpy-f32 bit-faithful ----------------
// one block per batch row; 256 threads = 32 l-groups(4 l) x 8 t-groups(5 t).
template <int USE_WR>
__global__ __launch_bounds__(256) void enc32_kernel(
    const float* __restrict__ x,  const float* __restrict__ w1,
    const float* __restrict__ b1, const float* __restrict__ w2,
    const float* __restrict__ w2r,
    const float* __restrict__ b2, float* __restrict__ zout)
{
    __shared__ float xp[FEAT + 4];        // xp[i] = x[i-1], zero-padded
    __shared__ float h1s[HID * HSTR];     // 44032 B; h2 tile aliased here too
    __shared__ float leafs[LAT * 8];      // 4096 B

    const int tid = threadIdx.x;
    const int b   = blockIdx.x;
    const int tx  = tid & 7;        // t-group (5 t's)
    const int ly  = tid >> 3;       // l-group (4 l's)
    const int u0  = tx * 5;

    const float wA = w1[tid*3+0], wB = w1[tid*3+1], wC = w1[tid*3+2];
    const float b1c = b1[tid];
    float b2v[4];
#pragma unroll
    for (int j = 0; j < 4; ++j) b2v[j] = b2[ly*4 + j];

    for (int i = tid; i < FEAT + 2; i += 256)
        xp[i] = (i >= 1 && i <= FEAT) ? x[(size_t)b*FEAT + i - 1] : 0.f;

    // numpy pairwise-840 leaf state (threads 0..127, one l each)
    float racc[8];
    int leaf_id = 0, leaf_pos = 0;
#pragma unroll
    for (int j = 0; j < 8; ++j) racc[j] = 0.f;

    __syncthreads();
    for (int t0 = 0; t0 < FEAT; t0 += T_SUB) {
        // ---- phase A: h1[c=tid][tp], f32 exact conv1 ----
        const bool edge = (t0 == 0) | (t0 + T_SUB == FEAT);
        if (edge) {
            for (int tp = 0; tp < T_SUB + 2; ++tp) {
                int tg = t0 - 1 + tp;
                float v = 0.f;
                if (tg >= 0 && tg < FEAT) {
                    float s = __fadd_rn(__fadd_rn(__fmul_rn(wA, xp[tg]),
                                                  __fmul_rn(wB, xp[tg+1])),
                                        __fmul_rn(wC, xp[tg+2]));
                    s = __fadd_rn(s, b1c);
                    v = s > 0.f ? s : 0.f;
                }
                h1s[tid*HSTR + tp] = v;
            }
        } else {
#pragma unroll 2
            for (int tp = 0; tp < T_SUB + 2; ++tp) {
                int tg = t0 - 1 + tp;
                float s = __fadd_rn(__fadd_rn(__fmul_rn(wA, xp[tg]),
                                              __fmul_rn(wB, xp[tg+1])),
                                    __fmul_rn(wC, xp[tg+2]));
                s = __fadd_rn(s, b1c);
                h1s[tid*HSTR + tp] = s > 0.f ? s : 0.f;
            }
        }
        __syncthreads();

        // ---- phase B: conv2, 4l x 5t, 3 k-chains each, c2 ascending ----
        float sk[4][5][3];
#pragma unroll
        for (int j = 0; j < 4; ++j)
#pragma unroll
            for (int i = 0; i < 5; ++i)
#pragma unroll
                for (int k = 0; k < 3; ++k) sk[j][i][k] = 0.f;

        if (USE_WR) {
            const float* __restrict__ wptr = w2r + ly*12;
            const float* __restrict__ hbase = &h1s[u0];
#pragma unroll 2
            for (int c2 = 0; c2 < HID; ++c2) {
                const float4* wp4 = (const float4*)(wptr + (size_t)c2*384);
                float4 a0 = wp4[0], a1 = wp4[1], a2 = wp4[2];
                const float* hb = hbase + c2*HSTR;
                float h0 = hb[0], h1v = hb[1], h2v = hb[2], h3 = hb[3];
                float h4 = hb[4], h5 = hb[5], h6 = hb[6];
                // j=0: (a0.x,a0.y,a0.z)  j=1: (a0.w,a1.x,a1.y)
                // j=2: (a1.z,a1.w,a2.x)  j=3: (a2.y,a2.z,a2.w)
                sk[0][0][0] = __fmaf_rn(a0.x, h0,  sk[0][0][0]);
                sk[0][0][1] = __fmaf_rn(a0.y, h1v, sk[0][0][1]);
                sk[0][0][2] = __fmaf_rn(a0.z, h2v, sk[0][0][2]);
                sk[0][1][0] = __fmaf_rn(a0.x, h1v, sk[0][1][0]);
                sk[0][1][1] = __fmaf_rn(a0.y, h2v, sk[0][1][1]);
                sk[0][1][2] = __fmaf_rn(a0.z, h3,  sk[0][1][2]);
                sk[0][2][0] = __fmaf_rn(a0.x, h2v, sk[0][2][0]);
                sk[0][2][1] = __fmaf_rn(a0.y, h3,  sk[0][2][1]);
                sk[0][2][2] = __fmaf_rn(a0.z, h4,  sk[0][2][2]);
                sk[0][3][0] = __fmaf_rn(a0.x, h3,  sk[0][3][0]);
                sk[0][3][1] = __fmaf_rn(a0.y, h4,  sk[0][3][1]);
                sk[0][3][2] = __fmaf_rn(a0.z, h5,  sk[0][3][2]);
                sk[0][4][0] = __fmaf_rn(a0.x, h4,  sk[0][4][0]);
                sk[0][4][1] = __fmaf_rn(a0.y, h5,  sk[0][4][1]);
                sk[0][4][2] = __fmaf_rn(a0.z, h6,  sk[0][4][2]);

                sk[1][0][0] = __fmaf_rn(a0.w, h0,  sk[1][0][0]);
                sk[1][0][1] = __fmaf_rn(a1.x, h1v, sk[1][0][1]);
                sk[1][0][2] = __fmaf_rn(a1.y, h2v, sk[1][0][2]);
                sk[1][1][0] = __fmaf_rn(a0.w, h1v, sk[1][1][0]);
                sk[1][1][1] = __fmaf_rn(a1.x, h2v, sk[1][1][1]);
                sk[1][1][2] = __fmaf_rn(a1.y, h3,  sk[1][1][2]);
                sk[1][2][0] = __fmaf_rn(a0.w, h2v, sk[1][2][0]);
                sk[1][2][1] = __fmaf_rn(a1.x, h3,  sk[1][2][1]);
                sk[1][2][2] = __fmaf_rn(a1.y, h4,  sk[1][2][2]);
                sk[1][3][0] = __fmaf_rn(a0.w, h3,  sk[1][3][0]);
                sk[1][3][1] = __fmaf_rn(a1.x, h4,  sk[1][3][1]);
                sk[1][3][2] = __fmaf_rn(a1.y, h5,  sk[1][3][2]);
                sk[1][4][0] = __fmaf_rn(a0.w, h4,  sk[1][4][0]);
                sk[1][4][1] = __fmaf_rn(a1.x, h5,  sk[1][4][1]);
                sk[1][4][2] = __fmaf_rn(a1.y, h6,  sk[1][4][2]);

                sk[2][0][0] = __fmaf_rn(a1.z, h0,  sk[2][0][0]);
                sk[2][0][1] = __fmaf_rn(a1.w, h1v, sk[2][0][1]);
                sk[2][0][2] = __fmaf_rn(a2.x, h2v, sk[2][0][2]);
                sk[2][1][0] = __fmaf_rn(a1.z, h1v, sk[2][1][0]);
                sk[2][1][1] = __fmaf_rn(a1.w, h2v, sk[2][1][1]);
                sk[2][1][2] = __fmaf_rn(a2.x, h3,  sk[2][1][2]);
                sk[2][2][0] = __fmaf_rn(a1.z, h2v, sk[2][2][0]);
                sk[2][2][1] = __fmaf_rn(a1.w, h3,  sk[2][2][1]);
                sk[2][2][2] = __fmaf_rn(a2.x, h4,  sk[2][2][2]);
                sk[2][3][0] = __fmaf_rn(a1.z, h3,  sk[2][3][0]);
                sk[2][3][1] = __fmaf_rn(a1.w, h4,  sk[2][3][1]);
                sk[2][3][2] = __fmaf_rn(a2.x, h5,  sk[2][3][2]);
                sk[2][4][0] = __fmaf_rn(a1.z, h4,  sk[2][4][0]);
                sk[2][4][1] = __fmaf_rn(a1.w, h5,  sk[2][4][1]);
                sk[2][4][2] = __fmaf_rn(a2.x, h6,  sk[2][4][2]);

                sk[3][0][0] = __fmaf_rn(a2.y, h0,  sk[3][0][0]);
                sk[3][0][1] = __fmaf_rn(a2.z, h1v, sk[3][0][1]);
                sk[3][0][2] = __fmaf_rn(a2.w, h2v, sk[3][0][2]);
                sk[3][1][0] = __fmaf_rn(a2.y, h1v, sk[3][1][0]);
                sk[3][1][1] = __fmaf_rn(a2.z, h2v, sk[3][1][1]);
                sk[3][1][2] = __fmaf_rn(a2.w, h3,  sk[3][1][2]);
                sk[3][2][0] = __fmaf_rn(a2.y, h2v, sk[3][2][0]);
                sk[3][2][1] = __fmaf_rn(a2.z, h3,  sk[3][2][1]);
                sk[3][2][2] = __fmaf_rn(a2.w, h4,  sk[3][2][2]);
                sk[3][3][0] = __fmaf_rn(a2.y, h3,  sk[3][3][0]);
                sk[3][3][1] = __fmaf_rn(a2.z, h4,  sk[3][3][1]);
                sk[3][3][2] = __fmaf_rn(a2.w, h5,  sk[3][3][2]);
                sk[3][4][0] = __fmaf_rn(a2.y, h4,  sk[3][4][0]);
                sk[3][4][1] = __fmaf_rn(a2.z, h5,  sk[3][4][1]);
                sk[3][4][2] = __fmaf_rn(a2.w, h6,  sk[3][4][2]);
            }
        } else {
            const float* __restrict__ wp = w2 + (size_t)(ly*4)*768;
            for (int c2 = 0; c2 < HID; ++c2) {
                const float* hb = &h1s[c2*HSTR + u0];
                float hv[7];
#pragma unroll
                for (int m = 0; m < 7; ++m) hv[m] = hb[m];
#pragma unroll
                for (int j = 0; j < 4; ++j) {
                    float wa = wp[j*768 + c2*3 + 0];
                    float wb = wp[j*768 + c2*3 + 1];
                    float wc = wp[j*768 + c2*3 + 2];
#pragma unroll
                    for (int i = 0; i < 5; ++i) {
                        sk[j][i][0] = __fmaf_rn(wa, hv[i],   sk[j][i][0]);
                        sk[j][i][1] = __fmaf_rn(wb, hv[i+1], sk[j][i][1]);
                        sk[j][i][2] = __fmaf_rn(wc, hv[i+2], sk[j][i][2]);
                    }
                }
            }
        }
        __syncthreads();   // all h1s reads done before h2 overwrites the region

        // h2 = fl(fl(m0+m1)+m2) + b2, relu  -> aliased LDS (h1s region)
#pragma unroll
        for (int j = 0; j < 4; ++j)
#pragma unroll
            for (int i = 0; i < 5; ++i) {
                float hh = __fadd_rn(__fadd_rn(sk[j][i][0], sk[j][i][1]), sk[j][i][2]);
                hh = __fadd_rn(hh, b2v[j]);
                hh = hh > 0.f ? hh : 0.f;
                h1s[(ly*4 + j)*H2STR + u0 + i] = hh;
            }
        __syncthreads();

        // reducer: threads 0..127 ingest 40 t's in order into numpy pairwise leaves
        if (tid < LAT) {
            for (int tt = 0; tt < T_SUB; ++tt) {
                float v = h1s[tid*H2STR + tt];
                int j = leaf_pos & 7;
                racc[j] = (leaf_pos < 8) ? v : __fadd_rn(racc[j], v);
                ++leaf_pos;
                int llen = (leaf_id == 7) ? 112 : 104;
                if (leaf_pos == llen) {
                    leafs[tid*8 + leaf_id] = np8_combine(racc);
                    ++leaf_id; leaf_pos = 0;
                }
            }
        }
        __syncthreads();   // reducer done before next tile's phase A writes h1s
    }

    // numpy pairwise-840 recombination
    if (tid < LAT) {
        const float* L = &leafs[tid*8];
        float s0 = __fadd_rn(L[0], L[1]);
        float s1 = __fadd_rn(L[2], L[3]);
        float sA = __fadd_rn(s0, s1);
        float s2 = __fadd_rn(L[4], L[5]);
        float s3 = __fadd_rn(L[6], L[7]);
        float sB = __fadd_rn(s2, s3);
        float tot = __fadd_rn(sA, sB);
        zout[(size_t)b*LAT + tid] = __fdiv_rn(tot, 840.0f);
    }
}

// ---------------- RVQ, numpy-f32 bit-faithful ----------------
__global__ __launch_bounds__(256) void rvq32_kernel(
    const float* __restrict__ cb, const float* __restrict__ z,
    float* __restrict__ zqout, float* __restrict__ oidx)
{
    __shared__ float rr[LAT];
    __shared__ float Ash;
    __shared__ float redd[256];
    __shared__ int   rede[256];
    __shared__ float sredd[64];
    __shared__ int   srede[64];
    __shared__ int   beste;
    __shared__ float qv[NQ * LAT];

    const int tid = threadIdx.x;
    const int b   = blockIdx.x;

    if (tid < LAT) rr[tid] = z[(size_t)b*LAT + tid];
    __syncthreads();

    for (int q = 0; q < NQ; ++q) {
        const float* __restrict__ cbq = cb + (size_t)q * NEMB * LAT;

        if (tid == 0) {
            float r8[8];
#pragma unroll
            for (int j = 0; j < 8; ++j) r8[j] = __fmul_rn(rr[j], rr[j]);
            for (int i = 8; i < LAT; i += 8)
#pragma unroll
                for (int j = 0; j < 8; ++j)
                    r8[j] = __fadd_rn(r8[j], __fmul_rn(rr[i+j], rr[i+j]));
            Ash = np8_combine(r8);
        }
        __syncthreads();

        float dmin = 0.f; int emin = 0;
#pragma unroll
        for (int h = 0; h < 2; ++h) {
            int e = 2*tid + h;
            const float* __restrict__ cp = cbq + (size_t)e*LAT;
            float dot = 0.f;
            float c8[8];
#pragma unroll
            for (int j = 0; j < 8; ++j) {
                float c = cp[j];
                c8[j] = __fmul_rn(c, c);
                dot = __fmaf_rn(c, rr[j], dot);
            }
            for (int i = 8; i < LAT; i += 8)
#pragma unroll
                for (int j = 0; j < 8; ++j) {
                    float c = cp[i+j];
                    dot = __fmaf_rn(c, rr[i+j], dot);
                    c8[j] = __fadd_rn(c8[j], __fmul_rn(c, c));
                }
            float cn = np8_combine(c8);
            float G  = __fmul_rn(2.0f, dot);
            float d  = __fadd_rn(__fsub_rn(Ash, G), cn);
            if (h == 0) { dmin = d; emin = e; }
            else if (d < dmin) { dmin = d; emin = e; }
        }
        redd[tid] = dmin; rede[tid] = emin;
        __syncthreads();

        if (tid < 64) {
            float bb = redd[tid*4]; int ee = rede[tid*4];
            for (int j = 1; j < 4; ++j) {
                float dj = redd[tid*4 + j];
                if (dj < bb) { bb = dj; ee = rede[tid*4 + j]; }
            }
            sredd[tid] = bb; srede[tid] = ee;
        }
        __syncthreads();
        if (tid == 0) {
            float bb = sredd[0]; int ee = srede[0];
            for (int j = 1; j < 64; ++j) {
                float dj = sredd[j];
                if (dj < bb) { bb = dj; ee = srede[j]; }
            }
            beste = ee;
            oidx[(size_t)b*NQ + q] = (float)ee;
        }
        __syncthreads();

        if (tid < LAT) {
            float cv = cbq[(size_t)beste*LAT + tid];
            qv[q*LAT + tid] = cv;
            rr[tid] = __fsub_rn(rr[tid], cv);
        }
        __syncthreads();
    }

    if (tid < LAT) {
        float s = qv[tid];
        for (int s2 = 1; s2 < NQ; ++s2)
            s = __fadd_rn(s, qv[s2*LAT + tid]);
        zqout[(size_t)b*LAT + tid] = s;
    }
}

extern "C" void kernel_launch(void* const* d_in, const int* in_sizes, int n_in,
                              void* d_out, int out_size, void* d_ws, size_t ws_size,
                              hipStream_t stream)
{
    (void)in_sizes; (void)n_in; (void)out_size;
    const float* x  = (const float*)d_in[0];
    const float* w1 = (const float*)d_in[1];
    const float* b1 = (const float*)d_in[2];
    const float* w2 = (const float*)d_in[3];
    const float* b2 = (const float*)d_in[4];
    const float* cb = (const float*)d_in[5];

    float* out  = (float*)d_out;
    float* zq   = out;                         // 2048*1*128 floats
    float* oidx = out + (size_t)B_SZ * LAT;    // 2048*1*12 floats

    const size_t w2r_bytes = (size_t)HID * 384 * sizeof(float);  // 393216

    if (ws_size >= w2r_bytes) {
        float* w2r = (float*)d_ws;
        w2r_kernel<<<(HID*384 + 255)/256, 256, 0, stream>>>(w2, w2r);
        enc32_kernel<1><<<B_SZ, 256, 0, stream>>>(x, w1, b1, w2, w2r, b2, zq);
    } else {
        enc32_kernel<0><<<B_SZ, 256, 0, stream>>>(x, w1, b1, w2, nullptr, b2, zq);
    }
    rvq32_kernel<<<B_SZ, 256, 0, stream>>>(cb, zq, zq, oidx);
}